// Round 1
// baseline (291.128 us; speedup 1.0000x reference)
//
#include <hip/hip_runtime.h>
#include <hip/hip_bf16.h>

typedef __bf16 bf16x8 __attribute__((ext_vector_type(8)));
typedef float  f32x4  __attribute__((ext_vector_type(4)));

#define B_   4
#define N_   4096
#define FIN  300
#define FOUT 300
#define FP   320   // padded feature / K dim (multiple of 32)

// ws layout (bytes)
#define WT_OFF   0                    // Wt  bf16 [FP][FP]          (~205 KB)
#define D_OFF    (512*1024)           // d   fp32 [B_*N_]           (64 KB)
#define TSC_OFF  (1024*1024)          // Tsc bf16 [B_*N_][FP]       (~10.5 MB)
#define YT_OFF   (16*1024*1024)       // Yt  bf16 [B_][FP][N_]      (~10.5 MB)

// ---------------- K0: Wt[f][k] = bf16(W[k][f]), zero-padded ----------------
__global__ void k_wt(const float* __restrict__ W, __bf16* __restrict__ Wt) {
    int t = blockIdx.x * 256 + threadIdx.x;
    if (t >= FP * FP) return;
    int f = t / FP, k = t - f * FP;
    float v = (f < FOUT && k < FIN) ? W[k * FOUT + f] : 0.0f;
    Wt[t] = (__bf16)v;
}

// ---------------- K1: d[row] = rsqrt(rowsum(adj)+1), one wave/row ----------
__global__ void k_rowsum(const float* __restrict__ adj, float* __restrict__ d) {
    int row  = blockIdx.x * 4 + (threadIdx.x >> 6);   // 16384 rows total
    int lane = threadIdx.x & 63;
    const float4* p = (const float4*)(adj + (size_t)row * N_);
    float s = 0.0f;
#pragma unroll
    for (int it = 0; it < 16; ++it) {
        float4 v = p[it * 64 + lane];
        s += v.x + v.y + v.z + v.w;
    }
#pragma unroll
    for (int off = 32; off; off >>= 1) s += __shfl_xor(s, off);
    if (lane == 0) d[row] = rsqrtf(s + 1.0f);
}

// ---------------- K2: Tsc[j][k] = bf16(d[j]*text[j][k]), K zero-padded -----
__global__ void k_tsc(const float* __restrict__ text, const float* __restrict__ d,
                      __bf16* __restrict__ Tsc) {
    int t = blockIdx.x * 256 + threadIdx.x;           // B_*N_*FP exact
    int j = t / FP;                                   // 0..16383 (b*N+j)
    int k = t - j * FP;
    float v = 0.0f;
    if (k < FIN) v = d[j] * text[(size_t)j * FIN + k];
    Tsc[t] = (__bf16)v;
}

// ---------------- K3: Yt[b][f][j] = sum_k Wt[f][k]*Tsc[b,j][k] -------------
// M=320(f) x N=64(j per block) x K=320. 4 waves: wave w = f-tiles [5w,5w+5).
__global__ __launch_bounds__(256) void k_y(const __bf16* __restrict__ Wt,
                                           const __bf16* __restrict__ Tsc,
                                           __bf16* __restrict__ Yt) {
    int b    = blockIdx.y;
    int j0   = blockIdx.x * 64;
    int wave = threadIdx.x >> 6, lane = threadIdx.x & 63;
    int lr = lane & 15, lg = lane >> 4;
    f32x4 acc[5][4] = {};
    for (int k0 = 0; k0 < FP; k0 += 32) {
        bf16x8 a[5], bb[4];
#pragma unroll
        for (int fi = 0; fi < 5; ++fi) {
            int f = (wave * 5 + fi) * 16 + lr;
            a[fi] = *(const bf16x8*)(Wt + (size_t)f * FP + k0 + lg * 8);
        }
#pragma unroll
        for (int ji = 0; ji < 4; ++ji) {
            int j = j0 + ji * 16 + lr;
            bb[ji] = *(const bf16x8*)(Tsc + ((size_t)(b * N_ + j)) * FP + k0 + lg * 8);
        }
#pragma unroll
        for (int fi = 0; fi < 5; ++fi)
#pragma unroll
            for (int ji = 0; ji < 4; ++ji)
                acc[fi][ji] = __builtin_amdgcn_mfma_f32_16x16x32_bf16(a[fi], bb[ji], acc[fi][ji], 0, 0, 0);
    }
#pragma unroll
    for (int fi = 0; fi < 5; ++fi)
#pragma unroll
        for (int ji = 0; ji < 4; ++ji)
#pragma unroll
            for (int r = 0; r < 4; ++r) {
                int f = (wave * 5 + fi) * 16 + lg * 4 + r;
                int j = j0 + ji * 16 + lr;
                Yt[((size_t)b * FP + f) * N_ + j] = (__bf16)acc[fi][ji][r];
            }
}

// ---------------- K4: out[b][i][f] = d_i * (adj_bf16 @ Yt) + bias ----------
// Block: 256 thr = 4 waves = (wm in {0,1}) x (wn in {0,1}).
// Wave tile: 2 m-tiles (32 rows) x 10 n-tiles (160 f cols). BM=64 per block.
#define LOAD_STAGE(AV, BV, K0)                                                        \
    {                                                                                 \
        _Pragma("unroll")                                                             \
        for (int mi = 0; mi < 2; ++mi) {                                              \
            const float4* p = (const float4*)(adjb + (size_t)(rowbase + mi * 16 + lr) * N_ + (K0) + lg * 8); \
            float4 v0 = p[0], v1 = p[1];                                              \
            AV[mi][0] = (__bf16)v0.x; AV[mi][1] = (__bf16)v0.y;                       \
            AV[mi][2] = (__bf16)v0.z; AV[mi][3] = (__bf16)v0.w;                       \
            AV[mi][4] = (__bf16)v1.x; AV[mi][5] = (__bf16)v1.y;                       \
            AV[mi][6] = (__bf16)v1.z; AV[mi][7] = (__bf16)v1.w;                       \
        }                                                                             \
        _Pragma("unroll")                                                             \
        for (int nt = 0; nt < 10; ++nt) {                                             \
            int f = wn * 160 + nt * 16 + lr;                                          \
            BV[nt] = *(const bf16x8*)(Yb + (size_t)f * N_ + (K0) + lg * 8);           \
        }                                                                             \
    }

#define MFMA_STAGE(AV, BV)                                                            \
    {                                                                                 \
        _Pragma("unroll")                                                             \
        for (int mi = 0; mi < 2; ++mi)                                                \
            _Pragma("unroll")                                                         \
            for (int nt = 0; nt < 10; ++nt)                                           \
                acc[mi][nt] = __builtin_amdgcn_mfma_f32_16x16x32_bf16(AV[mi], BV[nt], acc[mi][nt], 0, 0, 0); \
    }

__global__ __launch_bounds__(256, 1) void k_gemm(const float* __restrict__ adj,
                                                 const __bf16* __restrict__ Yt,
                                                 const float* __restrict__ d,
                                                 const float* __restrict__ bias,
                                                 float* __restrict__ out) {
    int b    = blockIdx.y;
    int wave = threadIdx.x >> 6, lane = threadIdx.x & 63;
    int wm = wave & 1, wn = wave >> 1;
    int lr = lane & 15, lg = lane >> 4;
    int rowbase = blockIdx.x * 64 + wm * 32;
    const float*  adjb = adj + (size_t)b * N_ * N_;
    const __bf16* Yb   = Yt + (size_t)b * FP * N_;

    f32x4 acc[2][10] = {};
    bf16x8 aA[2], bA[10], aB[2], bB[10];

    LOAD_STAGE(aA, bA, 0)
    for (int k0 = 0; k0 < N_ - 64; k0 += 64) {
        LOAD_STAGE(aB, bB, k0 + 32)
        MFMA_STAGE(aA, bA)
        LOAD_STAGE(aA, bA, k0 + 64)
        MFMA_STAGE(aB, bB)
    }
    LOAD_STAGE(aB, bB, N_ - 32)
    MFMA_STAGE(aA, bA)
    MFMA_STAGE(aB, bB)

    // epilogue: scale by d_i, add bias, store (f < 300 only)
#pragma unroll
    for (int mi = 0; mi < 2; ++mi) {
        float di[4];
#pragma unroll
        for (int r = 0; r < 4; ++r)
            di[r] = d[b * N_ + rowbase + mi * 16 + lg * 4 + r];
#pragma unroll
        for (int nt = 0; nt < 10; ++nt) {
            int f = wn * 160 + nt * 16 + lr;
            if (f < FOUT) {
                float bv = bias[f];
#pragma unroll
                for (int r = 0; r < 4; ++r) {
                    int i = rowbase + mi * 16 + lg * 4 + r;
                    out[((size_t)b * N_ + i) * FOUT + f] = di[r] * acc[mi][nt][r] + bv;
                }
            }
        }
    }
}

extern "C" void kernel_launch(void* const* d_in, const int* in_sizes, int n_in,
                              void* d_out, int out_size, void* d_ws, size_t ws_size,
                              hipStream_t stream) {
    const float* text = (const float*)d_in[0];
    const float* adj  = (const float*)d_in[1];
    const float* W    = (const float*)d_in[2];
    const float* bias = (const float*)d_in[3];
    float* out = (float*)d_out;

    char* ws = (char*)d_ws;
    __bf16* Wt  = (__bf16*)(ws + WT_OFF);
    float*  dv  = (float*)(ws + D_OFF);
    __bf16* Tsc = (__bf16*)(ws + TSC_OFF);
    __bf16* Yt  = (__bf16*)(ws + YT_OFF);

    k_wt<<<dim3((FP * FP + 255) / 256), dim3(256), 0, stream>>>(W, Wt);
    k_rowsum<<<dim3(B_ * N_ / 4), dim3(256), 0, stream>>>(adj, dv);
    k_tsc<<<dim3(B_ * N_ * FP / 256), dim3(256), 0, stream>>>(text, dv, Tsc);
    k_y<<<dim3(N_ / 64, B_), dim3(256), 0, stream>>>(Wt, Tsc, Yt);
    k_gemm<<<dim3(N_ / 64, B_), dim3(256), 0, stream>>>(adj, Yt, dv, bias, out);
}